// Round 1
// baseline (1135.653 us; speedup 1.0000x reference)
//
#include <hip/hip_runtime.h>

#define NTOK   8192     // B*T
#define DM     1024     // d_model = K dim of all GEMMs
#define HD_    1024     // H*dh
#define TSEQ   4096
#define NH     16
#define DH     64
#define CHUNK  64
#define NCH    64       // TSEQ / CHUNK
#define SSTRIDE 8320    // 2*64*64 + 2*64 floats per (bh, chunk) state
#define ANG_STEP 3.8349519697141029e-4f   // pi / (2*4096)

// ---------------------------------------------------------------------------
// GEMM: out[M=8192, N=1024] = A[8192,1024] @ W[1024,1024] + bias, optional ReLU
// 128x128 tile, BK=8, 256 threads, 8x8 per thread, fp32.
// ---------------------------------------------------------------------------
__global__ __launch_bounds__(256) void gemm_bias_act(
    const float* __restrict__ A, const float* __restrict__ W,
    const float* __restrict__ bias, float* __restrict__ out, int do_relu)
{
    __shared__ float As[8][132];   // pad 132: write stride breaks bank conflicts
    __shared__ float Bs[8][128];
    const int tid = threadIdx.x;
    const int bm = blockIdx.x, bn = blockIdx.y;
    const int m0 = (tid >> 4) << 3;
    const int n0 = (tid & 15) << 3;
    const int ar = tid >> 1, ac = (tid & 1) << 2;   // A tile: 128 rows x 8 k
    const int br = tid >> 5, bc = (tid & 31) << 2;  // B tile: 8 k x 128 cols
    const float* Ag = A + (size_t)(bm * 128 + ar) * DM + ac;
    const float* Wg = W + (size_t)br * HD_ + bn * 128 + bc;

    float acc[8][8];
#pragma unroll
    for (int i = 0; i < 8; ++i)
#pragma unroll
        for (int j = 0; j < 8; ++j) acc[i][j] = 0.f;

    for (int kt = 0; kt < DM / 8; ++kt) {
        float4 av = *(const float4*)(Ag + kt * 8);
        float4 bv = *(const float4*)(Wg + (size_t)kt * 8 * HD_);
        __syncthreads();
        As[ac + 0][ar] = av.x;
        As[ac + 1][ar] = av.y;
        As[ac + 2][ar] = av.z;
        As[ac + 3][ar] = av.w;
        *(float4*)&Bs[br][bc] = bv;
        __syncthreads();
#pragma unroll
        for (int k = 0; k < 8; ++k) {
            float4 a0 = *(const float4*)&As[k][m0];
            float4 a1 = *(const float4*)&As[k][m0 + 4];
            float4 b0 = *(const float4*)&Bs[k][n0];
            float4 b1 = *(const float4*)&Bs[k][n0 + 4];
            float a[8] = {a0.x, a0.y, a0.z, a0.w, a1.x, a1.y, a1.z, a1.w};
            float b[8] = {b0.x, b0.y, b0.z, b0.w, b1.x, b1.y, b1.z, b1.w};
#pragma unroll
            for (int i = 0; i < 8; ++i)
#pragma unroll
                for (int j = 0; j < 8; ++j)
                    acc[i][j] = fmaf(a[i], b[j], acc[i][j]);
        }
    }

#pragma unroll
    for (int i = 0; i < 8; ++i) {
        size_t row = (size_t)(bm * 128 + m0 + i);
#pragma unroll
        for (int j4 = 0; j4 < 8; j4 += 4) {
            float4 v;
            v.x = acc[i][j4 + 0] + bias[bn * 128 + n0 + j4 + 0];
            v.y = acc[i][j4 + 1] + bias[bn * 128 + n0 + j4 + 1];
            v.z = acc[i][j4 + 2] + bias[bn * 128 + n0 + j4 + 2];
            v.w = acc[i][j4 + 3] + bias[bn * 128 + n0 + j4 + 3];
            if (do_relu) {
                v.x = fmaxf(v.x, 0.f); v.y = fmaxf(v.y, 0.f);
                v.z = fmaxf(v.z, 0.f); v.w = fmaxf(v.w, 0.f);
            }
            *(float4*)(out + row * HD_ + bn * 128 + n0 + j4) = v;
        }
    }
}

// ---------------------------------------------------------------------------
// Phase A: per-(b,h,chunk) sums  Scos = sum_t kc_t (x) v_t, Ssin, zc, zs
// grid (NCH, B*H), 256 threads
// ---------------------------------------------------------------------------
__global__ __launch_bounds__(256) void chunk_sums_kernel(
    const float* __restrict__ Kp, const float* __restrict__ V,
    float* __restrict__ states)
{
    __shared__ float Kl[64][64];
    __shared__ float Vl[64][64];
    __shared__ float cw[64], sw[64];
    const int c = blockIdx.x, bh = blockIdx.y;
    const int b = bh >> 4, h = bh & 15;
    const int tid = threadIdx.x;
    const int r = tid >> 2;
    const int q4 = (tid & 3) << 4;
    const size_t gbase = (size_t)(b * TSEQ + c * CHUNK + r) * HD_ + h * DH + q4;
#pragma unroll
    for (int d = 0; d < 4; ++d) {
        *(float4*)&Kl[r][q4 + 4 * d] = *(const float4*)(Kp + gbase + 4 * d);
        *(float4*)&Vl[r][q4 + 4 * d] = *(const float4*)(V + gbase + 4 * d);
    }
    if (tid < 64) {
        float s_, c_;
        sincosf(ANG_STEP * (float)(c * CHUNK + tid), &s_, &c_);
        sw[tid] = s_; cw[tid] = c_;
    }
    __syncthreads();

    float4 sc[4], ss[4];
#pragma unroll
    for (int d = 0; d < 4; ++d) {
        sc[d] = make_float4(0.f, 0.f, 0.f, 0.f);
        ss[d] = make_float4(0.f, 0.f, 0.f, 0.f);
    }
    for (int t = 0; t < 64; ++t) {
        float kp = Kl[t][r];
        float kc = kp * cw[t], ks = kp * sw[t];
#pragma unroll
        for (int d = 0; d < 4; ++d) {
            float4 v4 = *(const float4*)&Vl[t][q4 + 4 * d];
            sc[d].x = fmaf(kc, v4.x, sc[d].x);
            sc[d].y = fmaf(kc, v4.y, sc[d].y);
            sc[d].z = fmaf(kc, v4.z, sc[d].z);
            sc[d].w = fmaf(kc, v4.w, sc[d].w);
            ss[d].x = fmaf(ks, v4.x, ss[d].x);
            ss[d].y = fmaf(ks, v4.y, ss[d].y);
            ss[d].z = fmaf(ks, v4.z, ss[d].z);
            ss[d].w = fmaf(ks, v4.w, ss[d].w);
        }
    }
    float* st = states + (size_t)(bh * NCH + c) * SSTRIDE;
#pragma unroll
    for (int d = 0; d < 4; ++d) {
        *(float4*)&st[r * 64 + q4 + 4 * d] = sc[d];
        *(float4*)&st[4096 + r * 64 + q4 + 4 * d] = ss[d];
    }
    if (tid < 64) {
        float zc = 0.f, zs = 0.f;
        for (int t = 0; t < 64; ++t) {
            float kp = Kl[t][tid];
            zc = fmaf(kp, cw[t], zc);
            zs = fmaf(kp, sw[t], zs);
        }
        st[8192 + tid] = zc;
        st[8256 + tid] = zs;
    }
}

// ---------------------------------------------------------------------------
// Phase B: in-place EXCLUSIVE prefix over chunks. grid (33, B*H), 256 thr
// ---------------------------------------------------------------------------
__global__ __launch_bounds__(256) void scan_kernel(float* __restrict__ states)
{
    const int e = blockIdx.x * 256 + threadIdx.x;
    const int bh = blockIdx.y;
    if (e >= SSTRIDE) return;
    float* p = states + (size_t)bh * (NCH * (size_t)SSTRIDE) + e;
    float run = 0.f;
    for (int c = 0; c < NCH; ++c) {
        float v = p[(size_t)c * SSTRIDE];
        p[(size_t)c * SSTRIDE] = run;
        run += v;
    }
}

// ---------------------------------------------------------------------------
// Phase C: intra-chunk causal attention + inter-chunk state; writes att
// in-place over Qp. grid (NCH, B*H), 256 threads.
// ---------------------------------------------------------------------------
__global__ __launch_bounds__(256) void attn_kernel(
    float* __restrict__ QpAtt, const float* __restrict__ Kp,
    const float* __restrict__ V, const float* __restrict__ states)
{
    __shared__ float Ql[64][68];   // padded: broadcast reads across 16 tt-groups
    __shared__ float KT[64][64];   // Kp^T; later reused for S_cos prefix
    __shared__ float Vl[64][64];
    __shared__ float Al[64][68];   // A scores; later reused for S_sin prefix
    __shared__ float cw[64], sw[64], zc[64], zs[64], den[64];
    __shared__ float den4[64][4];

    const int c = blockIdx.x, bh = blockIdx.y;
    const int b = bh >> 4, h = bh & 15;
    const int tid = threadIdx.x;
    const int r = tid >> 2;
    const int q4 = (tid & 3) << 4;
    const size_t gbase = (size_t)(b * TSEQ + c * CHUNK + r) * HD_ + h * DH + q4;
    const float* st = states + (size_t)(bh * NCH + c) * SSTRIDE;

#pragma unroll
    for (int d = 0; d < 4; ++d) {
        float4 qv = *(const float4*)(QpAtt + gbase + 4 * d);
        *(float4*)&Ql[r][q4 + 4 * d] = qv;
        float4 vv = *(const float4*)(V + gbase + 4 * d);
        *(float4*)&Vl[r][q4 + 4 * d] = vv;
        float4 kv = *(const float4*)(Kp + gbase + 4 * d);
        KT[q4 + 4 * d + 0][r] = kv.x;
        KT[q4 + 4 * d + 1][r] = kv.y;
        KT[q4 + 4 * d + 2][r] = kv.z;
        KT[q4 + 4 * d + 3][r] = kv.w;
    }
    if (tid < 64) {
        float s_, c_;
        sincosf(ANG_STEP * (float)(c * CHUNK + tid), &s_, &c_);
        sw[tid] = s_; cw[tid] = c_;
        zc[tid] = st[8192 + tid];
        zs[tid] = st[8256 + tid];
    }
    __syncthreads();

    const int tt = r, s0 = q4;
    // ---- Step 2: A[tt][s] = (Qp[tt].Kp[s]) * cos(th_tt - th_s), causal mask
    float dot[16];
#pragma unroll
    for (int d = 0; d < 16; ++d) dot[d] = 0.f;
    for (int i = 0; i < 64; ++i) {
        float qv = Ql[tt][i];
#pragma unroll
        for (int u = 0; u < 4; ++u) {
            float4 k4 = *(const float4*)&KT[i][s0 + 4 * u];
            dot[4 * u + 0] = fmaf(qv, k4.x, dot[4 * u + 0]);
            dot[4 * u + 1] = fmaf(qv, k4.y, dot[4 * u + 1]);
            dot[4 * u + 2] = fmaf(qv, k4.z, dot[4 * u + 2]);
            dot[4 * u + 3] = fmaf(qv, k4.w, dot[4 * u + 3]);
        }
    }
    const float cwt = cw[tt], swt = sw[tt];
    float part = 0.f;
#pragma unroll
    for (int d = 0; d < 16; ++d) {
        int s = s0 + d;
        float f = fmaf(cwt, cw[s], swt * sw[s]);
        float a = (s <= tt) ? dot[d] * f : 0.f;
        Al[tt][s] = a;
        part += a;
    }
    // denominator: inter-chunk z contribution (split over the 4 threads per tt)
#pragma unroll
    for (int d = 0; d < 16; ++d) {
        int i = s0 + d;
        part = fmaf(Ql[tt][i], fmaf(cwt, zc[i], swt * sw[0] * 0.f + swt * zs[i]), part);
    }
    den4[tt][tid & 3] = part;
    __syncthreads();
    if (tid < 64)
        den[tid] = fmaxf(den4[tid][0] + den4[tid][1] + den4[tid][2] + den4[tid][3], 1e-6f);

    // ---- Step 3a: intra-chunk num
    float o[16];
#pragma unroll
    for (int d = 0; d < 16; ++d) o[d] = 0.f;
    for (int s = 0; s < 64; ++s) {
        float a = Al[tt][s];
#pragma unroll
        for (int u = 0; u < 4; ++u) {
            float4 v4 = *(const float4*)&Vl[s][q4 + 4 * u];
            o[4 * u + 0] = fmaf(a, v4.x, o[4 * u + 0]);
            o[4 * u + 1] = fmaf(a, v4.y, o[4 * u + 1]);
            o[4 * u + 2] = fmaf(a, v4.z, o[4 * u + 2]);
            o[4 * u + 3] = fmaf(a, v4.w, o[4 * u + 3]);
        }
    }
    __syncthreads();   // A, KT dead; den written

    // ---- load exclusive-prefix states into the dead buffers
#pragma unroll
    for (int d = 0; d < 4; ++d) {
        *(float4*)&KT[r][q4 + 4 * d] = *(const float4*)(st + r * 64 + q4 + 4 * d);          // S_cos
        *(float4*)&Al[r][q4 + 4 * d] = *(const float4*)(st + 4096 + r * 64 + q4 + 4 * d);   // S_sin
    }
    __syncthreads();

    // ---- Step 3b: inter-chunk num
    for (int i = 0; i < 64; ++i) {
        float qv = Ql[tt][i];
        float qc = qv * cwt, qs = qv * swt;
#pragma unroll
        for (int u = 0; u < 4; ++u) {
            float4 c4 = *(const float4*)&KT[i][q4 + 4 * u];
            float4 s4 = *(const float4*)&Al[i][q4 + 4 * u];
            o[4 * u + 0] = fmaf(qc, c4.x, fmaf(qs, s4.x, o[4 * u + 0]));
            o[4 * u + 1] = fmaf(qc, c4.y, fmaf(qs, s4.y, o[4 * u + 1]));
            o[4 * u + 2] = fmaf(qc, c4.z, fmaf(qs, s4.z, o[4 * u + 2]));
            o[4 * u + 3] = fmaf(qc, c4.w, fmaf(qs, s4.w, o[4 * u + 3]));
        }
    }

    // ---- Step 4: divide by denominator, write att in-place over Qp
    const float dv = den[tt];
#pragma unroll
    for (int u = 0; u < 4; ++u) {
        float4 w;
        w.x = o[4 * u + 0] / dv;
        w.y = o[4 * u + 1] / dv;
        w.z = o[4 * u + 2] / dv;
        w.w = o[4 * u + 3] / dv;
        *(float4*)(QpAtt + gbase + 4 * u) = w;
    }
}

// ---------------------------------------------------------------------------
extern "C" void kernel_launch(void* const* d_in, const int* in_sizes, int n_in,
                              void* d_out, int out_size, void* d_ws, size_t ws_size,
                              hipStream_t stream)
{
    const float* x  = (const float*)d_in[0];
    const float* Wq = (const float*)d_in[1];
    const float* bq = (const float*)d_in[2];
    const float* Wk = (const float*)d_in[3];
    const float* bk = (const float*)d_in[4];
    const float* Wv = (const float*)d_in[5];
    const float* bv = (const float*)d_in[6];
    const float* Wo = (const float*)d_in[7];
    const float* bo = (const float*)d_in[8];
    float* out = (float*)d_out;

    float* ws = (float*)d_ws;
    float* Qp = ws;                         // N*HD floats; becomes att in-place
    float* Kp = ws + (size_t)NTOK * HD_;
    float* Vb = ws + 2 * (size_t)NTOK * HD_;
    float* states = ws + 3 * (size_t)NTOK * HD_;  // B*H*NCH*SSTRIDE floats

    dim3 gg(64, 8), tb(256);
    hipLaunchKernelGGL(gemm_bias_act, gg, tb, 0, stream, x, Wq, bq, Qp, 1);
    hipLaunchKernelGGL(gemm_bias_act, gg, tb, 0, stream, x, Wk, bk, Kp, 1);
    hipLaunchKernelGGL(gemm_bias_act, gg, tb, 0, stream, x, Wv, bv, Vb, 0);
    hipLaunchKernelGGL(chunk_sums_kernel, dim3(NCH, 32), tb, 0, stream, Kp, Vb, states);
    hipLaunchKernelGGL(scan_kernel, dim3(33, 32), tb, 0, stream, states);
    hipLaunchKernelGGL(attn_kernel, dim3(NCH, 32), tb, 0, stream, Qp, Kp, Vb, states);
    hipLaunchKernelGGL(gemm_bias_act, gg, tb, 0, stream, Qp, Wo, bo, out, 0);
}

// Round 2
// 355.091 us; speedup vs baseline: 3.1982x; 3.1982x over previous
//
#include <hip/hip_runtime.h>

#define NTOK   8192     // B*T
#define DM     1024     // d_model = K dim of all GEMMs
#define HD_    1024     // H*dh
#define TSEQ   4096
#define NH     16
#define DH     64
#define CHUNK  64
#define NCH    64       // TSEQ / CHUNK
#define SSTRIDE 8320    // 2*64*64 + 2*64 floats per (bh, chunk) state
#define ANG_STEP 3.8349519697141029e-4f   // pi / (2*4096)

typedef _Float16 h8_t __attribute__((ext_vector_type(8)));
typedef _Float16 h4_t __attribute__((ext_vector_type(4)));
typedef float    f32x4 __attribute__((ext_vector_type(4)));

__device__ __forceinline__ void gload16(const void* g, void* l) {
    __builtin_amdgcn_global_load_lds(
        (const __attribute__((address_space(1))) void*)g,
        (__attribute__((address_space(3))) void*)l, 16, 0, 0);
}

// ---------------------------------------------------------------------------
// f16 MFMA GEMM core: out[M,1024] = A[M,1024] @ Wt^T + bias (Wt is [N][K] f16)
// 128x128 tile, BK=32, 256 threads (4 waves, 2x2), 4x4 16x16x32 frags/wave.
// ---------------------------------------------------------------------------
__device__ __forceinline__ void gemm_core(
    const _Float16* __restrict__ A, const _Float16* __restrict__ Wt,
    const float* __restrict__ bias, float* __restrict__ out, int relu,
    _Float16 (*As)[32], _Float16 (*Bs)[32])
{
    const int tid = threadIdx.x;
    const int lane = tid & 63, w = tid >> 6;
    const int m_base = blockIdx.x * 128, n_base = blockIdx.y * 128;

    // staging map: tile byte lin = tid*16 (+4096 for second half); row=lin/64
    const int r0 = tid >> 2;               // rows 0..63
    const int cb0 = (tid & 3) << 4;        // byte col 0/16/32/48
    const _Float16* ga = A  + (size_t)(m_base + r0) * DM + (cb0 >> 1);
    const _Float16* gb = Wt + (size_t)(n_base + r0) * DM + (cb0 >> 1);
    char* lA = (char*)As + w * 1024;       // wave-uniform LDS base
    char* lB = (char*)Bs + w * 1024;

    f32x4 acc[4][4];
#pragma unroll
    for (int i = 0; i < 4; ++i)
#pragma unroll
        for (int j = 0; j < 4; ++j) acc[i][j] = (f32x4){0.f, 0.f, 0.f, 0.f};

    const int wm = (w >> 1) * 64, wn = (w & 1) * 64;
    const int fr = lane & 15;
    const int fk = (lane >> 4) * 16;       // byte offset into 64B row

    for (int kt = 0; kt < DM / 32; ++kt) {
        const int k0 = kt * 32;
        __syncthreads();
        gload16(ga + k0,             lA);
        gload16(ga + 64 * DM + k0,   lA + 4096);
        gload16(gb + k0,             lB);
        gload16(gb + 64 * DM + k0,   lB + 4096);
        __syncthreads();
        h8_t a[4], b[4];
#pragma unroll
        for (int i = 0; i < 4; ++i) {
            a[i] = *(const h8_t*)((const char*)&As[wm + i * 16 + fr][0] + fk);
            b[i] = *(const h8_t*)((const char*)&Bs[wn + i * 16 + fr][0] + fk);
        }
#pragma unroll
        for (int i = 0; i < 4; ++i)
#pragma unroll
            for (int j = 0; j < 4; ++j)
                acc[i][j] = __builtin_amdgcn_mfma_f32_16x16x32_f16(a[i], b[j], acc[i][j], 0, 0, 0);
    }

    // C/D layout (m89-verified): col = lane&15, row = (lane>>4)*4 + reg
    const int cn = lane & 15, rm = (lane >> 4) * 4;
#pragma unroll
    for (int j = 0; j < 4; ++j) {
        const int col = n_base + wn + j * 16 + cn;
        const float bs = bias[col];
#pragma unroll
        for (int i = 0; i < 4; ++i) {
#pragma unroll
            for (int r = 0; r < 4; ++r) {
                const size_t row = (size_t)(m_base + wm + i * 16 + rm + r);
                float v = acc[i][j][r] + bs;
                if (relu) v = fmaxf(v, 0.f);
                out[row * HD_ + col] = v;
            }
        }
    }
}

__global__ __launch_bounds__(256) void gemm_f16_qkv(
    const _Float16* __restrict__ Xh, const _Float16* __restrict__ WtQKV,
    const float* __restrict__ bq, const float* __restrict__ bk, const float* __restrict__ bv,
    float* __restrict__ Qp, float* __restrict__ Kp, float* __restrict__ Vb)
{
    __shared__ _Float16 As[128][32];
    __shared__ _Float16 Bs[128][32];
    const int z = blockIdx.z;
    const _Float16* Wt = WtQKV + (size_t)z * (DM * HD_);
    const float* bias = (z == 0) ? bq : (z == 1) ? bk : bv;
    float* out = (z == 0) ? Qp : (z == 1) ? Kp : Vb;
    gemm_core(Xh, Wt, bias, out, (z < 2) ? 1 : 0, As, Bs);
}

__global__ __launch_bounds__(256) void gemm_f16_single(
    const _Float16* __restrict__ A, const _Float16* __restrict__ Wt,
    const float* __restrict__ bias, float* __restrict__ out)
{
    __shared__ _Float16 As[128][32];
    __shared__ _Float16 Bs[128][32];
    gemm_core(A, Wt, bias, out, 0, As, Bs);
}

// ---------------------------------------------------------------------------
// fp32 -> f16 convert (x), and fp32 W[K][N] -> f16 Wt[N][K] transpose-convert
// ---------------------------------------------------------------------------
__global__ __launch_bounds__(256) void conv_x_kernel(
    const float* __restrict__ x, _Float16* __restrict__ xh)
{
    const int i = blockIdx.x * 256 + threadIdx.x;   // per float4
    float4 v = ((const float4*)x)[i];
    h4_t h;
    h[0] = (_Float16)v.x; h[1] = (_Float16)v.y;
    h[2] = (_Float16)v.z; h[3] = (_Float16)v.w;
    ((h4_t*)xh)[i] = h;
}

__global__ __launch_bounds__(256) void conv_wt_kernel(
    const float* __restrict__ W, _Float16* __restrict__ Wt)
{
    __shared__ float t[32][33];
    const int bx = blockIdx.x * 32, by = blockIdx.y * 32;  // bx: n, by: k
    const int tx = threadIdx.x, ty = threadIdx.y;          // 32 x 8
#pragma unroll
    for (int i = 0; i < 4; ++i)
        t[ty + 8 * i][tx] = W[(size_t)(by + ty + 8 * i) * HD_ + bx + tx];
    __syncthreads();
#pragma unroll
    for (int i = 0; i < 4; ++i)
        Wt[(size_t)(bx + ty + 8 * i) * DM + by + tx] = (_Float16)t[tx][ty + 8 * i];
}

// ---------------------------------------------------------------------------
// Phase A: per-(b,h,chunk) sums  Scos = sum_t kc_t (x) v_t, Ssin, zc, zs
// ---------------------------------------------------------------------------
__global__ __launch_bounds__(256) void chunk_sums_kernel(
    const float* __restrict__ Kp, const float* __restrict__ V,
    float* __restrict__ states)
{
    __shared__ float Kl[64][64];
    __shared__ float Vl[64][64];
    __shared__ float cw[64], sw[64];
    const int c = blockIdx.x, bh = blockIdx.y;
    const int b = bh >> 4, h = bh & 15;
    const int tid = threadIdx.x;
    const int r = tid >> 2;
    const int q4 = (tid & 3) << 4;
    const size_t gbase = (size_t)(b * TSEQ + c * CHUNK + r) * HD_ + h * DH + q4;
#pragma unroll
    for (int d = 0; d < 4; ++d) {
        *(float4*)&Kl[r][q4 + 4 * d] = *(const float4*)(Kp + gbase + 4 * d);
        *(float4*)&Vl[r][q4 + 4 * d] = *(const float4*)(V + gbase + 4 * d);
    }
    if (tid < 64) {
        float s_, c_;
        sincosf(ANG_STEP * (float)(c * CHUNK + tid), &s_, &c_);
        sw[tid] = s_; cw[tid] = c_;
    }
    __syncthreads();

    float4 sc[4], ss[4];
#pragma unroll
    for (int d = 0; d < 4; ++d) {
        sc[d] = make_float4(0.f, 0.f, 0.f, 0.f);
        ss[d] = make_float4(0.f, 0.f, 0.f, 0.f);
    }
    for (int t = 0; t < 64; ++t) {
        float kp = Kl[t][r];
        float kc = kp * cw[t], ks = kp * sw[t];
#pragma unroll
        for (int d = 0; d < 4; ++d) {
            float4 v4 = *(const float4*)&Vl[t][q4 + 4 * d];
            sc[d].x = fmaf(kc, v4.x, sc[d].x);
            sc[d].y = fmaf(kc, v4.y, sc[d].y);
            sc[d].z = fmaf(kc, v4.z, sc[d].z);
            sc[d].w = fmaf(kc, v4.w, sc[d].w);
            ss[d].x = fmaf(ks, v4.x, ss[d].x);
            ss[d].y = fmaf(ks, v4.y, ss[d].y);
            ss[d].z = fmaf(ks, v4.z, ss[d].z);
            ss[d].w = fmaf(ks, v4.w, ss[d].w);
        }
    }
    float* st = states + (size_t)(bh * NCH + c) * SSTRIDE;
#pragma unroll
    for (int d = 0; d < 4; ++d) {
        *(float4*)&st[r * 64 + q4 + 4 * d] = sc[d];
        *(float4*)&st[4096 + r * 64 + q4 + 4 * d] = ss[d];
    }
    if (tid < 64) {
        float zc = 0.f, zs = 0.f;
        for (int t = 0; t < 64; ++t) {
            float kp = Kl[t][tid];
            zc = fmaf(kp, cw[t], zc);
            zs = fmaf(kp, sw[t], zs);
        }
        st[8192 + tid] = zc;
        st[8256 + tid] = zs;
    }
}

// ---------------------------------------------------------------------------
// Phase B: in-place EXCLUSIVE prefix over chunks
// ---------------------------------------------------------------------------
__global__ __launch_bounds__(256) void scan_kernel(float* __restrict__ states)
{
    const int e = blockIdx.x * 256 + threadIdx.x;
    const int bh = blockIdx.y;
    if (e >= SSTRIDE) return;
    float* p = states + (size_t)bh * (NCH * (size_t)SSTRIDE) + e;
    float run = 0.f;
    for (int c = 0; c < NCH; ++c) {
        float v = p[(size_t)c * SSTRIDE];
        p[(size_t)c * SSTRIDE] = run;
        run += v;
    }
}

// ---------------------------------------------------------------------------
// Phase C: intra-chunk causal attention + inter-chunk state -> f16 att
// ---------------------------------------------------------------------------
__global__ __launch_bounds__(256) void attn_kernel(
    const float* __restrict__ Qp, const float* __restrict__ Kp,
    const float* __restrict__ V, const float* __restrict__ states,
    _Float16* __restrict__ atth)
{
    __shared__ float Ql[64][68];
    __shared__ float KT[64][64];   // Kp^T; later reused for S_cos prefix
    __shared__ float Vl[64][64];
    __shared__ float Al[64][68];   // A scores; later reused for S_sin prefix
    __shared__ float cw[64], sw[64], zc[64], zs[64], den[64];
    __shared__ float den4[64][4];

    const int c = blockIdx.x, bh = blockIdx.y;
    const int b = bh >> 4, h = bh & 15;
    const int tid = threadIdx.x;
    const int r = tid >> 2;
    const int q4 = (tid & 3) << 4;
    const size_t gbase = (size_t)(b * TSEQ + c * CHUNK + r) * HD_ + h * DH + q4;
    const float* st = states + (size_t)(bh * NCH + c) * SSTRIDE;

#pragma unroll
    for (int d = 0; d < 4; ++d) {
        float4 qv = *(const float4*)(Qp + gbase + 4 * d);
        *(float4*)&Ql[r][q4 + 4 * d] = qv;
        float4 vv = *(const float4*)(V + gbase + 4 * d);
        *(float4*)&Vl[r][q4 + 4 * d] = vv;
        float4 kv = *(const float4*)(Kp + gbase + 4 * d);
        KT[q4 + 4 * d + 0][r] = kv.x;
        KT[q4 + 4 * d + 1][r] = kv.y;
        KT[q4 + 4 * d + 2][r] = kv.z;
        KT[q4 + 4 * d + 3][r] = kv.w;
    }
    if (tid < 64) {
        float s_, c_;
        sincosf(ANG_STEP * (float)(c * CHUNK + tid), &s_, &c_);
        sw[tid] = s_; cw[tid] = c_;
        zc[tid] = st[8192 + tid];
        zs[tid] = st[8256 + tid];
    }
    __syncthreads();

    const int tt = r, s0 = q4;
    float dot[16];
#pragma unroll
    for (int d = 0; d < 16; ++d) dot[d] = 0.f;
    for (int i = 0; i < 64; ++i) {
        float qv = Ql[tt][i];
#pragma unroll
        for (int u = 0; u < 4; ++u) {
            float4 k4 = *(const float4*)&KT[i][s0 + 4 * u];
            dot[4 * u + 0] = fmaf(qv, k4.x, dot[4 * u + 0]);
            dot[4 * u + 1] = fmaf(qv, k4.y, dot[4 * u + 1]);
            dot[4 * u + 2] = fmaf(qv, k4.z, dot[4 * u + 2]);
            dot[4 * u + 3] = fmaf(qv, k4.w, dot[4 * u + 3]);
        }
    }
    const float cwt = cw[tt], swt = sw[tt];
    float part = 0.f;
#pragma unroll
    for (int d = 0; d < 16; ++d) {
        int s = s0 + d;
        float f = fmaf(cwt, cw[s], swt * sw[s]);
        float a = (s <= tt) ? dot[d] * f : 0.f;
        Al[tt][s] = a;
        part += a;
    }
#pragma unroll
    for (int d = 0; d < 16; ++d) {
        int i = s0 + d;
        part = fmaf(Ql[tt][i], fmaf(cwt, zc[i], swt * zs[i]), part);
    }
    den4[tt][tid & 3] = part;
    __syncthreads();
    if (tid < 64)
        den[tid] = fmaxf(den4[tid][0] + den4[tid][1] + den4[tid][2] + den4[tid][3], 1e-6f);

    float o[16];
#pragma unroll
    for (int d = 0; d < 16; ++d) o[d] = 0.f;
    for (int s = 0; s < 64; ++s) {
        float a = Al[tt][s];
#pragma unroll
        for (int u = 0; u < 4; ++u) {
            float4 v4 = *(const float4*)&Vl[s][q4 + 4 * u];
            o[4 * u + 0] = fmaf(a, v4.x, o[4 * u + 0]);
            o[4 * u + 1] = fmaf(a, v4.y, o[4 * u + 1]);
            o[4 * u + 2] = fmaf(a, v4.z, o[4 * u + 2]);
            o[4 * u + 3] = fmaf(a, v4.w, o[4 * u + 3]);
        }
    }
    __syncthreads();   // A, KT dead; den written

#pragma unroll
    for (int d = 0; d < 4; ++d) {
        *(float4*)&KT[r][q4 + 4 * d] = *(const float4*)(st + r * 64 + q4 + 4 * d);          // S_cos
        *(float4*)&Al[r][q4 + 4 * d] = *(const float4*)(st + 4096 + r * 64 + q4 + 4 * d);   // S_sin
    }
    __syncthreads();

    for (int i = 0; i < 64; ++i) {
        float qv = Ql[tt][i];
        float qc = qv * cwt, qs = qv * swt;
#pragma unroll
        for (int u = 0; u < 4; ++u) {
            float4 c4 = *(const float4*)&KT[i][q4 + 4 * u];
            float4 s4 = *(const float4*)&Al[i][q4 + 4 * u];
            o[4 * u + 0] = fmaf(qc, c4.x, fmaf(qs, s4.x, o[4 * u + 0]));
            o[4 * u + 1] = fmaf(qc, c4.y, fmaf(qs, s4.y, o[4 * u + 1]));
            o[4 * u + 2] = fmaf(qc, c4.z, fmaf(qs, s4.z, o[4 * u + 2]));
            o[4 * u + 3] = fmaf(qc, c4.w, fmaf(qs, s4.w, o[4 * u + 3]));
        }
    }

    const float dv = den[tt];
#pragma unroll
    for (int u = 0; u < 4; ++u) {
        h4_t w;
        w[0] = (_Float16)(o[4 * u + 0] / dv);
        w[1] = (_Float16)(o[4 * u + 1] / dv);
        w[2] = (_Float16)(o[4 * u + 2] / dv);
        w[3] = (_Float16)(o[4 * u + 3] / dv);
        *(h4_t*)(atth + gbase + 4 * u) = w;
    }
}

// ---------------------------------------------------------------------------
extern "C" void kernel_launch(void* const* d_in, const int* in_sizes, int n_in,
                              void* d_out, int out_size, void* d_ws, size_t ws_size,
                              hipStream_t stream)
{
    const float* x  = (const float*)d_in[0];
    const float* Wq = (const float*)d_in[1];
    const float* bq = (const float*)d_in[2];
    const float* Wk = (const float*)d_in[3];
    const float* bk = (const float*)d_in[4];
    const float* Wv = (const float*)d_in[5];
    const float* bv = (const float*)d_in[6];
    const float* Wo = (const float*)d_in[7];
    const float* bo = (const float*)d_in[8];
    float* out = (float*)d_out;

    float* ws = (float*)d_ws;
    float* Qp = ws;                                   // NTOK*HD_ f32
    float* Kp = Qp + (size_t)NTOK * HD_;
    float* Vb = Kp + (size_t)NTOK * HD_;
    float* states = Vb + (size_t)NTOK * HD_;          // 32*64*SSTRIDE f32
    _Float16* Xh = (_Float16*)(states + (size_t)32 * NCH * SSTRIDE);  // NTOK*HD_ f16
    _Float16* atth = Xh;                              // alias: Xh dead after QKV GEMMs
    _Float16* WtQKV = Xh + (size_t)NTOK * HD_;        // 3 * DM*HD_ f16
    _Float16* WtO = WtQKV + 3 * (size_t)DM * HD_;     // DM*HD_ f16

    dim3 tb(256);
    hipLaunchKernelGGL(conv_x_kernel, dim3(NTOK * HD_ / 1024), tb, 0, stream, x, Xh);
    hipLaunchKernelGGL(conv_wt_kernel, dim3(32, 32), dim3(32, 8), 0, stream, Wq, WtQKV);
    hipLaunchKernelGGL(conv_wt_kernel, dim3(32, 32), dim3(32, 8), 0, stream, Wk, WtQKV + (size_t)DM * HD_);
    hipLaunchKernelGGL(conv_wt_kernel, dim3(32, 32), dim3(32, 8), 0, stream, Wv, WtQKV + 2 * (size_t)DM * HD_);
    hipLaunchKernelGGL(conv_wt_kernel, dim3(32, 32), dim3(32, 8), 0, stream, Wo, WtO);
    hipLaunchKernelGGL(gemm_f16_qkv, dim3(64, 8, 3), tb, 0, stream,
                       Xh, WtQKV, bq, bk, bv, Qp, Kp, Vb);
    hipLaunchKernelGGL(chunk_sums_kernel, dim3(NCH, 32), tb, 0, stream, Kp, Vb, states);
    hipLaunchKernelGGL(scan_kernel, dim3(33, 32), tb, 0, stream, states);
    hipLaunchKernelGGL(attn_kernel, dim3(NCH, 32), tb, 0, stream, Qp, Kp, Vb, states, atth);
    hipLaunchKernelGGL(gemm_f16_single, dim3(64, 8), tb, 0, stream, atth, WtO, bo, out);
}

// Round 3
// 298.741 us; speedup vs baseline: 3.8015x; 1.1886x over previous
//
#include <hip/hip_runtime.h>

#define NTOK   8192     // B*T
#define DM     1024     // d_model
#define HD_    1024     // H*dh
#define TSEQ   4096
#define NCH    64       // TSEQ / 64
#define SROWS  72       // rows per state half ([d][i] 0-63, z row 64, pad 65-71)
#define SHALF  (SROWS*64)       // 4608 f16
#define SSTR   (2*SHALF)        // 9216 f16 per (bh,c)
#define ANG_STEP 3.8349519697141029e-4f   // pi / (2*4096)

typedef _Float16 h8_t  __attribute__((ext_vector_type(8)));
typedef _Float16 h4_t  __attribute__((ext_vector_type(4)));
typedef float    f32x4 __attribute__((ext_vector_type(4)));

__device__ __forceinline__ void gload16(const void* g, void* l) {
    __builtin_amdgcn_global_load_lds(
        (const __attribute__((address_space(1))) void*)g,
        (__attribute__((address_space(3))) void*)l, 16, 0, 0);
}

// ---------------------------------------------------------------------------
// f16 MFMA GEMM core (round-2-verified loop). Epilogue modes:
//  0: f16 rows + relu (Q)   1: f16 rows + relu + [bh][d][T] packs (K)
//  2: [bh][d][T] packs only (V)   3: f32 rows (final out)
// ---------------------------------------------------------------------------
__device__ __forceinline__ void gemm_core(
    const _Float16* __restrict__ A, const _Float16* __restrict__ Wt,
    const float* __restrict__ bias, int mode,
    _Float16* rows16, _Float16* tp16, float* rows32,
    _Float16 (*As)[32], _Float16 (*Bs)[32])
{
    const int tid = threadIdx.x;
    const int lane = tid & 63, w = tid >> 6;
    const int m_base = blockIdx.x * 128, n_base = blockIdx.y * 128;

    const int r0 = tid >> 2;
    const int cb0 = (tid & 3) << 4;
    const _Float16* ga = A  + (size_t)(m_base + r0) * DM + (cb0 >> 1);
    const _Float16* gb = Wt + (size_t)(n_base + r0) * DM + (cb0 >> 1);
    char* lA = (char*)As + w * 1024;
    char* lB = (char*)Bs + w * 1024;

    f32x4 acc[4][4];
#pragma unroll
    for (int i = 0; i < 4; ++i)
#pragma unroll
        for (int j = 0; j < 4; ++j) acc[i][j] = (f32x4){0.f, 0.f, 0.f, 0.f};

    const int wm = (w >> 1) * 64, wn = (w & 1) * 64;
    const int fr = lane & 15;
    const int fk = (lane >> 4) * 16;

    for (int kt = 0; kt < DM / 32; ++kt) {
        const int k0 = kt * 32;
        __syncthreads();
        gload16(ga + k0,           lA);
        gload16(ga + 64 * DM + k0, lA + 4096);
        gload16(gb + k0,           lB);
        gload16(gb + 64 * DM + k0, lB + 4096);
        __syncthreads();
        h8_t a[4], b[4];
#pragma unroll
        for (int i = 0; i < 4; ++i) {
            a[i] = *(const h8_t*)((const char*)&As[wm + i * 16 + fr][0] + fk);
            b[i] = *(const h8_t*)((const char*)&Bs[wn + i * 16 + fr][0] + fk);
        }
#pragma unroll
        for (int i = 0; i < 4; ++i)
#pragma unroll
            for (int j = 0; j < 4; ++j)
                acc[i][j] = __builtin_amdgcn_mfma_f32_16x16x32_f16(a[i], b[j], acc[i][j], 0, 0, 0);
    }

    const int cn = lane & 15, rm = (lane >> 4) * 4;
#pragma unroll
    for (int j = 0; j < 4; ++j) {
        const int col = n_base + wn + j * 16 + cn;
        const float bs = bias[col];
#pragma unroll
        for (int i = 0; i < 4; ++i) {
            const int m0 = m_base + wm + i * 16 + rm;
            if (mode == 3) {
#pragma unroll
                for (int r = 0; r < 4; ++r)
                    rows32[(size_t)(m0 + r) * HD_ + col] = acc[i][j][r] + bs;
            } else {
                float v[4];
#pragma unroll
                for (int r = 0; r < 4; ++r) {
                    v[r] = acc[i][j][r] + bs;
                    if (mode <= 1) v[r] = fmaxf(v[r], 0.f);
                }
                if (mode <= 1) {
#pragma unroll
                    for (int r = 0; r < 4; ++r)
                        rows16[(size_t)(m0 + r) * HD_ + col] = (_Float16)v[r];
                }
                if (mode >= 1) {
                    h4_t pk;
#pragma unroll
                    for (int r = 0; r < 4; ++r) pk[r] = (_Float16)v[r];
                    const int bb = m0 >> 12, t = m0 & 4095;
                    const int hh = col >> 6, dd = col & 63;
                    *(h4_t*)(tp16 + ((size_t)(bb * 16 + hh) * 64 + dd) * TSEQ + t) = pk;
                }
            }
        }
    }
}

__global__ __launch_bounds__(256) void gemm_qkv(
    const _Float16* __restrict__ Xh, const _Float16* __restrict__ WtQKV,
    const float* __restrict__ bq, const float* __restrict__ bk, const float* __restrict__ bv,
    _Float16* __restrict__ Qh, _Float16* __restrict__ Kh,
    _Float16* __restrict__ KT, _Float16* __restrict__ VT)
{
    __shared__ _Float16 As[128][32];
    __shared__ _Float16 Bs[128][32];
    const int z = blockIdx.z;
    const _Float16* Wt = WtQKV + (size_t)z * (DM * HD_);
    const float* bias = (z == 0) ? bq : (z == 1) ? bk : bv;
    _Float16* r16 = (z == 0) ? Qh : Kh;
    _Float16* t16 = (z == 1) ? KT : VT;
    gemm_core(Xh, Wt, bias, z, r16, t16, nullptr, As, Bs);
}

__global__ __launch_bounds__(256) void gemm_out(
    const _Float16* __restrict__ A, const _Float16* __restrict__ Wt,
    const float* __restrict__ bias, float* __restrict__ out)
{
    __shared__ _Float16 As[128][32];
    __shared__ _Float16 Bs[128][32];
    gemm_core(A, Wt, bias, 3, nullptr, nullptr, out, As, Bs);
}

// ---------------------------------------------------------------------------
// converts
// ---------------------------------------------------------------------------
__global__ __launch_bounds__(256) void conv_x_kernel(
    const float* __restrict__ x, _Float16* __restrict__ xh)
{
    const int i = blockIdx.x * 256 + threadIdx.x;
    float4 v = ((const float4*)x)[i];
    h4_t hv;
    hv[0] = (_Float16)v.x; hv[1] = (_Float16)v.y;
    hv[2] = (_Float16)v.z; hv[3] = (_Float16)v.w;
    ((h4_t*)xh)[i] = hv;
}

__global__ __launch_bounds__(256) void conv_wt4(
    const float* __restrict__ Wq, const float* __restrict__ Wk,
    const float* __restrict__ Wv, const float* __restrict__ Wo,
    _Float16* __restrict__ WtQKV, _Float16* __restrict__ WtO)
{
    __shared__ float t[32][33];
    const int z = blockIdx.z;
    const float* W = (z == 0) ? Wq : (z == 1) ? Wk : (z == 2) ? Wv : Wo;
    _Float16* Wt = (z < 3) ? WtQKV + (size_t)z * DM * HD_ : WtO;
    const int bx = blockIdx.x * 32, by = blockIdx.y * 32;
    const int tx = threadIdx.x, ty = threadIdx.y;
#pragma unroll
    for (int i = 0; i < 4; ++i)
        t[ty + 8 * i][tx] = W[(size_t)(by + ty + 8 * i) * HD_ + bx + tx];
    __syncthreads();
#pragma unroll
    for (int i = 0; i < 4; ++i)
        Wt[(size_t)(bx + ty + 8 * i) * DM + by + tx] = (_Float16)t[tx][ty + 8 * i];
}

// ---------------------------------------------------------------------------
// chunk_sums: states^T[d][i] (f16, transposed) + z row via ones-row MFMA trick
// grid (NCH, 32), 256 threads
// ---------------------------------------------------------------------------
__global__ __launch_bounds__(256) void chunk_sums(
    const _Float16* __restrict__ KT, const _Float16* __restrict__ VT,
    _Float16* __restrict__ states)
{
    __shared__ char sm[26880];
    _Float16* cwh = (_Float16*)(sm);        // 64 f16
    _Float16* swh = (_Float16*)(sm + 128);
    #define CS_KC 256
    #define CS_KS 8448
    #define CS_VT 16640   // 66 rows + overrun pad to row 79 inside sm

    const int c = blockIdx.x, bh = blockIdx.y;
    const int tid = threadIdx.x, lane = tid & 63, w = tid >> 6;

    if (tid < 64) {
        float s_, c_;
        sincosf(ANG_STEP * (float)(c * 64 + tid), &s_, &c_);
        cwh[tid] = (_Float16)c_; swh[tid] = (_Float16)s_;
    }
    __syncthreads();

    // stage K^T tile with cos/sin scaling (reg-staged, swizzled writes)
    const size_t ktb = (size_t)(bh * 64) * TSEQ + c * 64;
#pragma unroll
    for (int rnd = 0; rnd < 2; ++rnd) {
        int lin = rnd * 256 + tid;
        int r = lin >> 3, u = lin & 7;
        h8_t kv = *(const h8_t*)(KT + ktb + (size_t)r * TSEQ + u * 8);
        h8_t c8 = *(const h8_t*)&cwh[u * 8];
        h8_t s8 = *(const h8_t*)&swh[u * 8];
        int sb = (r * 128 + u * 16) ^ ((r & 7) << 4);
        *(h8_t*)(sm + CS_KC + sb) = kv * c8;
        *(h8_t*)(sm + CS_KS + sb) = kv * s8;
    }
    // stage V^T tile via gload16 with pre-swizzled source
    const _Float16* vtb = VT + (size_t)(bh * 64) * TSEQ + c * 64;
#pragma unroll
    for (int rnd = 0; rnd < 2; ++rnd) {
        int lin = rnd * 256 + tid;
        int r = lin >> 3, u = lin & 7;
        gload16(vtb + (size_t)r * TSEQ + (u ^ (r & 7)) * 8,
                sm + CS_VT + (rnd * 256 + w * 64) * 16);
    }
    if (tid < 8) {
        h8_t one;
#pragma unroll
        for (int e = 0; e < 8; ++e) one[e] = (_Float16)1.0f;
        *(h8_t*)(sm + CS_VT + 64 * 128 + tid * 16) = one;  // ones row -> z
    }
    __syncthreads();

    const int fr = lane & 15, rm = (lane >> 4) * 4;
    _Float16* stc = states + (size_t)(bh * NCH + c) * SSTR;

    for (int half = 0; half < 2; ++half) {
        const int ko = half ? CS_KS : CS_KC;
        f32x4 acc[4][5];
#pragma unroll
        for (int i = 0; i < 4; ++i)
#pragma unroll
            for (int j = 0; j < 5; ++j) acc[i][j] = (f32x4){0.f, 0.f, 0.f, 0.f};
#pragma unroll
        for (int ks = 0; ks < 2; ++ks) {
            const int fko = ks * 64 + (lane >> 4) * 16;
            h8_t af[4], bf[5];
#pragma unroll
            for (int i = 0; i < 4; ++i) {
                int row = i * 16 + fr;
                af[i] = *(const h8_t*)(sm + ko + ((row * 128 + fko) ^ ((row & 7) << 4)));
            }
#pragma unroll
            for (int j = 0; j < 5; ++j) {
                int row = j * 16 + fr;
                bf[j] = *(const h8_t*)(sm + CS_VT + ((row * 128 + fko) ^ ((row & 7) << 4)));
            }
#pragma unroll
            for (int i = 0; i < 4; ++i)
#pragma unroll
                for (int j = 0; j < 5; ++j)
                    acc[i][j] = __builtin_amdgcn_mfma_f32_16x16x32_f16(af[i], bf[j], acc[i][j], 0, 0, 0);
        }
        // D[m=i][n=d|z]; store S^T[d][i] as 8B packs
        _Float16* dst = stc + half * SHALF;
#pragma unroll
        for (int j = 0; j < 5; ++j) {
            int n = j * 16 + fr;
#pragma unroll
            for (int i = 0; i < 4; ++i) {
                h4_t pk;
#pragma unroll
                for (int r = 0; r < 4; ++r) pk[r] = (_Float16)acc[i][j][r];
                if (n <= 64) *(h4_t*)(dst + (size_t)n * 64 + i * 16 + rm) = pk;
            }
        }
    }
}

// ---------------------------------------------------------------------------
// exclusive prefix over chunks, f16 state, fp32 running sums. grid (5,32)
// ---------------------------------------------------------------------------
__global__ __launch_bounds__(256) void scan_kernel(_Float16* __restrict__ states)
{
    const int e8 = blockIdx.x * 256 + threadIdx.x;
    if (e8 >= SSTR / 8) return;
    _Float16* p = states + (size_t)blockIdx.y * (NCH * (size_t)SSTR) + (size_t)e8 * 8;
    float run[8];
#pragma unroll
    for (int e = 0; e < 8; ++e) run[e] = 0.f;
    for (int c = 0; c < NCH; ++c) {
        h8_t v = *(const h8_t*)(p + (size_t)c * SSTR);
        h8_t ov;
#pragma unroll
        for (int e = 0; e < 8; ++e) {
            ov[e] = (_Float16)run[e];
            run[e] += (float)v[e];
        }
        *(h8_t*)(p + (size_t)c * SSTR) = ov;
    }
}

// ---------------------------------------------------------------------------
// MFMA attention: QK^T -> mask/scale -> (A.V + Qc.Sc + Qs.Ss) with den column
// grid (NCH, 32), 256 threads, ~52KB LDS -> 3 blocks/CU
// ---------------------------------------------------------------------------
__global__ __launch_bounds__(256) void attn_mfma(
    const _Float16* __restrict__ Qh, const _Float16* __restrict__ Kh,
    const _Float16* __restrict__ VT, const _Float16* __restrict__ states,
    _Float16* __restrict__ atth)
{
    __shared__ char sm[53248];
    float* cwf = (float*)(sm);
    float* swf = (float*)(sm + 256);
    _Float16* cwh = (_Float16*)(sm + 512);
    _Float16* swh = (_Float16*)(sm + 640);
    #define AT_Q 768
    #define AT_K 8960
    #define AT_A 17152
    #define AT_V 25344
    #define AT_C 33792
    #define AT_S 43008

    const int c = blockIdx.x, bh = blockIdx.y;
    const int b = bh >> 4, h = bh & 15;
    const int tid = threadIdx.x, lane = tid & 63, w = tid >> 6;
    const int tok0 = b * TSEQ + c * 64;

    if (tid < 64) {
        float s_, c_;
        sincosf(ANG_STEP * (float)(c * 64 + tid), &s_, &c_);
        cwf[tid] = c_; swf[tid] = s_;
        cwh[tid] = (_Float16)c_; swh[tid] = (_Float16)s_;
    }

    const _Float16* stb = states + (size_t)(bh * NCH + c) * SSTR;
#pragma unroll
    for (int rnd = 0; rnd < 2; ++rnd) {
        int lin = rnd * 256 + tid;
        int r = lin >> 3, u = lin & 7;
        int su = (u ^ (r & 7)) * 8;
        char* lb = sm + (rnd * 256 + w * 64) * 16;
        gload16(Qh + (size_t)(tok0 + r) * HD_ + h * 64 + su, lb + AT_Q);
        gload16(Kh + (size_t)(tok0 + r) * HD_ + h * 64 + su, lb + AT_K);
        gload16(VT + (size_t)(bh * 64 + r) * TSEQ + c * 64 + su, lb + AT_V);
    }
#pragma unroll
    for (int rnd = 0; rnd < 3; ++rnd) {
        if (rnd < 2 || tid < 64) {
            int lin = rnd * 256 + tid;
            int r = lin >> 3, u = lin & 7;
            int su = (u ^ (r & 7)) * 8;
            char* lb = sm + (rnd * 256 + w * 64) * 16;
            gload16(stb + (size_t)r * 64 + su, lb + AT_C);
            gload16(stb + SHALF + (size_t)r * 64 + su, lb + AT_S);
        }
    }
    if (tid < 8) {
        h8_t one;
#pragma unroll
        for (int e = 0; e < 8; ++e) one[e] = (_Float16)1.0f;
        *(h8_t*)(sm + AT_V + 64 * 128 + tid * 16) = one;
    }
    __syncthreads();

    const int fr = lane & 15;
    // ---- QK^T: D[s][tt] = K.Q^T
    f32x4 dt[4][4];
#pragma unroll
    for (int i = 0; i < 4; ++i)
#pragma unroll
        for (int j = 0; j < 4; ++j) dt[i][j] = (f32x4){0.f, 0.f, 0.f, 0.f};
#pragma unroll
    for (int ks = 0; ks < 2; ++ks) {
        const int fko = ks * 64 + (lane >> 4) * 16;
        h8_t ak[4], bq[4];
#pragma unroll
        for (int i = 0; i < 4; ++i) {
            int row = i * 16 + fr;
            int sb = (row * 128 + fko) ^ ((row & 7) << 4);
            ak[i] = *(const h8_t*)(sm + AT_K + sb);
            bq[i] = *(const h8_t*)(sm + AT_Q + sb);
        }
#pragma unroll
        for (int i = 0; i < 4; ++i)
#pragma unroll
            for (int j = 0; j < 4; ++j)
                dt[i][j] = __builtin_amdgcn_mfma_f32_16x16x32_f16(ak[i], bq[j], dt[i][j], 0, 0, 0);
    }
    // ---- mask + cos-reweight, write A[tt][s] f16 (swizzled)
    {
        const int sr0 = (lane >> 4) * 4;
#pragma unroll
        for (int j = 0; j < 4; ++j) {
            const int tt = j * 16 + fr;
            const float cwt = cwf[tt], swt = swf[tt];
#pragma unroll
            for (int i = 0; i < 4; ++i) {
                const int s0 = i * 16 + sr0;
                h4_t pk;
#pragma unroll
                for (int r = 0; r < 4; ++r) {
                    int s = s0 + r;
                    float f = cwt * cwf[s] + swt * swf[s];
                    float a = (s <= tt) ? dt[i][j][r] * f : 0.f;
                    pk[r] = (_Float16)a;
                }
                int sb = (tt * 128 + s0 * 2) ^ ((tt & 7) << 4);
                *(h4_t*)(sm + AT_A + sb) = pk;
            }
        }
    }
    __syncthreads();

    // ---- O = A.V + Qc.ScT^T + Qs.SsT^T ; col 64 = den (intra + inter)
    f32x4 o[4][5];
#pragma unroll
    for (int i = 0; i < 4; ++i)
#pragma unroll
        for (int j = 0; j < 5; ++j) o[i][j] = (f32x4){0.f, 0.f, 0.f, 0.f};
#pragma unroll
    for (int ks = 0; ks < 2; ++ks) {
        const int fko = ks * 64 + (lane >> 4) * 16;
        h8_t aa[4], aqc[4], aqs[4];
#pragma unroll
        for (int i = 0; i < 4; ++i) {
            int row = i * 16 + fr;
            int sb = (row * 128 + fko) ^ ((row & 7) << 4);
            aa[i] = *(const h8_t*)(sm + AT_A + sb);
            h8_t q8 = *(const h8_t*)(sm + AT_Q + sb);
            aqc[i] = q8 * cwh[row];
            aqs[i] = q8 * swh[row];
        }
#pragma unroll
        for (int j = 0; j < 5; ++j) {
            int row = j * 16 + fr;
            int sb = (row * 128 + fko) ^ ((row & 7) << 4);
            h8_t bv = *(const h8_t*)(sm + AT_V + sb);
            h8_t bc = *(const h8_t*)(sm + AT_C + sb);
            h8_t bs = *(const h8_t*)(sm + AT_S + sb);
#pragma unroll
            for (int i = 0; i < 4; ++i) {
                o[i][j] = __builtin_amdgcn_mfma_f32_16x16x32_f16(aa[i],  bv, o[i][j], 0, 0, 0);
                o[i][j] = __builtin_amdgcn_mfma_f32_16x16x32_f16(aqc[i], bc, o[i][j], 0, 0, 0);
                o[i][j] = __builtin_amdgcn_mfma_f32_16x16x32_f16(aqs[i], bs, o[i][j], 0, 0, 0);
            }
        }
    }
    // ---- den broadcast + write
    const int rm = (lane >> 4) * 4;
#pragma unroll
    for (int i = 0; i < 4; ++i) {
        float rden[4];
#pragma unroll
        for (int r = 0; r < 4; ++r)
            rden[r] = 1.0f / fmaxf(__shfl(o[i][4][r], lane & 48), 1e-6f);
#pragma unroll
        for (int j = 0; j < 4; ++j) {
            const int dcol = h * 64 + j * 16 + fr;
#pragma unroll
            for (int r = 0; r < 4; ++r)
                atth[(size_t)(tok0 + i * 16 + rm + r) * HD_ + dcol] =
                    (_Float16)(o[i][j][r] * rden[r]);
        }
    }
}

// ---------------------------------------------------------------------------
extern "C" void kernel_launch(void* const* d_in, const int* in_sizes, int n_in,
                              void* d_out, int out_size, void* d_ws, size_t ws_size,
                              hipStream_t stream)
{
    const float* x  = (const float*)d_in[0];
    const float* Wq = (const float*)d_in[1];
    const float* bq = (const float*)d_in[2];
    const float* Wk = (const float*)d_in[3];
    const float* bk = (const float*)d_in[4];
    const float* Wv = (const float*)d_in[5];
    const float* bv = (const float*)d_in[6];
    const float* Wo = (const float*)d_in[7];
    const float* bo = (const float*)d_in[8];
    float* out = (float*)d_out;

    _Float16* ws = (_Float16*)d_ws;
    _Float16* Xh     = ws;                                  // NTOK*DM
    _Float16* WtQKV  = Xh + (size_t)NTOK * DM;              // 3*DM*HD_
    _Float16* WtO    = WtQKV + 3 * (size_t)DM * HD_;        // DM*HD_
    _Float16* Qh     = WtO + (size_t)DM * HD_;              // NTOK*HD_
    _Float16* Kh     = Qh + (size_t)NTOK * HD_;
    _Float16* KT     = Kh + (size_t)NTOK * HD_;             // [bh][64][4096]
    _Float16* VT     = KT + (size_t)NTOK * HD_;
    _Float16* atth   = VT + (size_t)NTOK * HD_;
    _Float16* states = atth + (size_t)NTOK * HD_;           // 32*64*SSTR

    dim3 tb(256);
    hipLaunchKernelGGL(conv_x_kernel, dim3(NTOK * DM / 1024), tb, 0, stream, x, Xh);
    hipLaunchKernelGGL(conv_wt4, dim3(32, 32, 4), dim3(32, 8), 0, stream,
                       Wq, Wk, Wv, Wo, WtQKV, WtO);
    hipLaunchKernelGGL(gemm_qkv, dim3(64, 8, 3), tb, 0, stream,
                       Xh, WtQKV, bq, bk, bv, Qh, Kh, KT, VT);
    hipLaunchKernelGGL(chunk_sums, dim3(NCH, 32), tb, 0, stream, KT, VT, states);
    hipLaunchKernelGGL(scan_kernel, dim3(5, 32), tb, 0, stream, states);
    hipLaunchKernelGGL(attn_mfma, dim3(NCH, 32), tb, 0, stream, Qh, Kh, VT, states, atth);
    hipLaunchKernelGGL(gemm_out, dim3(64, 8), tb, 0, stream, atth, WtO, bo, out);
}

// Round 4
// 297.080 us; speedup vs baseline: 3.8227x; 1.0056x over previous
//
#include <hip/hip_runtime.h>

#define NTOK   8192     // B*T
#define DM     1024     // d_model
#define HD_    1024     // H*dh
#define TSEQ   4096
#define NCH    64       // TSEQ / 64
#define SROWS  72       // rows per state half ([d][i] 0-63, z row 64, pad 65-71)
#define SHALF  (SROWS*64)       // 4608 f16
#define SSTR   (2*SHALF)        // 9216 f16 per (bh,c)
#define ANG_STEP 3.8349519697141029e-4f   // pi / (2*4096)

typedef _Float16 h8_t  __attribute__((ext_vector_type(8)));
typedef _Float16 h4_t  __attribute__((ext_vector_type(4)));
typedef float    f32x4 __attribute__((ext_vector_type(4)));

__device__ __forceinline__ void gload16(const void* g, void* l) {
    __builtin_amdgcn_global_load_lds(
        (const __attribute__((address_space(1))) void*)g,
        (__attribute__((address_space(3))) void*)l, 16, 0, 0);
}

// ---------------------------------------------------------------------------
// f16 MFMA GEMM core. sm layout: As [0,8K), Bs [8K,16K), Ct [16K,48K).
// Epilogue modes: 0: f16 rows+relu (Q)  1: rows+relu + [bh][d][T] packs (K)
//                 2: packs only (V)     3: f32 rows (final out)
// All f16 outputs flushed via LDS-staged coalesced h8 stores.
// ---------------------------------------------------------------------------
__device__ __forceinline__ void gemm_core(
    const _Float16* __restrict__ A, const _Float16* __restrict__ Wt,
    const float* __restrict__ bias, int mode,
    _Float16* rows16, _Float16* tp16, float* rows32, char* sm)
{
    const int tid = threadIdx.x;
    const int lane = tid & 63, w = tid >> 6;
    const int m_base = blockIdx.x * 128, n_base = blockIdx.y * 128;

    const int r0 = tid >> 2;
    const int cb0 = (tid & 3) << 4;
    const _Float16* ga = A  + (size_t)(m_base + r0) * DM + (cb0 >> 1);
    const _Float16* gb = Wt + (size_t)(n_base + r0) * DM + (cb0 >> 1);
    char* lA = sm + w * 1024;
    char* lB = sm + 8192 + w * 1024;
    char* Ct = sm + 16384;

    f32x4 acc[4][4];
#pragma unroll
    for (int i = 0; i < 4; ++i)
#pragma unroll
        for (int j = 0; j < 4; ++j) acc[i][j] = (f32x4){0.f, 0.f, 0.f, 0.f};

    const int wm = (w >> 1) * 64, wn = (w & 1) * 64;
    const int fr = lane & 15;
    const int fk = (lane >> 4) * 16;

    for (int kt = 0; kt < DM / 32; ++kt) {
        const int k0 = kt * 32;
        __syncthreads();
        gload16(ga + k0,           lA);
        gload16(ga + 64 * DM + k0, lA + 4096);
        gload16(gb + k0,           lB);
        gload16(gb + 64 * DM + k0, lB + 4096);
        __syncthreads();
        h8_t a[4], b[4];
#pragma unroll
        for (int i = 0; i < 4; ++i) {
            a[i] = *(const h8_t*)(sm + (wm + i * 16 + fr) * 64 + fk);
            b[i] = *(const h8_t*)(sm + 8192 + (wn + i * 16 + fr) * 64 + fk);
        }
#pragma unroll
        for (int i = 0; i < 4; ++i)
#pragma unroll
            for (int j = 0; j < 4; ++j)
                acc[i][j] = __builtin_amdgcn_mfma_f32_16x16x32_f16(a[i], b[j], acc[i][j], 0, 0, 0);
    }

    // D layout (verified): col = lane&15 (+j*16), row = (lane>>4)*4 + reg (+i*16)
    const int rm = (lane >> 4) * 4;
    if (mode == 3) {
#pragma unroll
        for (int j = 0; j < 4; ++j) {
            const int col = n_base + wn + j * 16 + fr;
            const float bs = bias[col];
#pragma unroll
            for (int i = 0; i < 4; ++i) {
                const int m0 = m_base + wm + i * 16 + rm;
#pragma unroll
                for (int r = 0; r < 4; ++r)
                    rows32[(size_t)(m0 + r) * HD_ + col] = acc[i][j][r] + bs;
            }
        }
        return;
    }

    // ---- Phase R: row-major flush (modes 0,1; always relu) ----
    if (mode <= 1) {
#pragma unroll
        for (int j = 0; j < 4; ++j) {
            const int col = wn + j * 16 + fr;          // local col 0..127
            const float bs = bias[n_base + col];
#pragma unroll
            for (int i = 0; i < 4; ++i) {
                const int ml0 = wm + i * 16 + rm;
#pragma unroll
                for (int r = 0; r < 4; ++r) {
                    const int mloc = ml0 + r;
                    const int byte = ((mloc << 8) + (col << 1)) ^ ((mloc & 15) << 4);
                    *(_Float16*)(Ct + byte) = (_Float16)fmaxf(acc[i][j][r] + bs, 0.f);
                }
            }
        }
        __syncthreads();
#pragma unroll
        for (int p = 0; p < 8; ++p) {
            const int lin = p * 256 + tid;
            const int t = lin >> 4, d8 = lin & 15;
            h8_t v = *(const h8_t*)(Ct + (t << 8) + ((d8 ^ (t & 15)) << 4));
            *(h8_t*)(rows16 + (size_t)(m_base + t) * HD_ + n_base + d8 * 8) = v;
        }
    }

    // ---- Phase T: [bh][d][T] transposed flush (modes 1,2) ----
    if (mode >= 1) {
        if (mode == 1) __syncthreads();
#pragma unroll
        for (int j = 0; j < 4; ++j) {
            const int col = wn + j * 16 + fr;
            const float bs = bias[n_base + col];
#pragma unroll
            for (int i = 0; i < 4; ++i) {
                const int ml0 = wm + i * 16 + rm;
                h4_t pk;
#pragma unroll
                for (int r = 0; r < 4; ++r) {
                    float v = acc[i][j][r] + bs;
                    if (mode == 1) v = fmaxf(v, 0.f);
                    pk[r] = (_Float16)v;
                }
                const int byte = ((col << 8) + (ml0 << 1)) ^ ((col & 15) << 4);
                *(h4_t*)(Ct + byte) = pk;
            }
        }
        __syncthreads();
        const int bb = m_base >> 12;
        const int tl0 = m_base & 4095;
#pragma unroll
        for (int p = 0; p < 8; ++p) {
            const int lin = p * 256 + tid;
            const int d = lin >> 4, t8 = lin & 15;
            h8_t v = *(const h8_t*)(Ct + (d << 8) + ((t8 ^ (d & 15)) << 4));
            const int colg = n_base + d;
            *(h8_t*)(tp16 + ((size_t)(bb * 16 + (colg >> 6)) * 64 + (colg & 63)) * TSEQ
                     + tl0 + t8 * 8) = v;
        }
    }
}

__global__ __launch_bounds__(256) void gemm_qkv(
    const _Float16* __restrict__ Xh, const _Float16* __restrict__ WtQKV,
    const float* __restrict__ bq, const float* __restrict__ bk, const float* __restrict__ bv,
    _Float16* __restrict__ Qh, _Float16* __restrict__ Kh,
    _Float16* __restrict__ KT, _Float16* __restrict__ VT)
{
    __shared__ char sm[49152];
    const int z = blockIdx.z;
    const _Float16* Wt = WtQKV + (size_t)z * (DM * HD_);
    const float* bias = (z == 0) ? bq : (z == 1) ? bk : bv;
    _Float16* r16 = (z == 0) ? Qh : Kh;
    _Float16* t16 = (z == 1) ? KT : VT;
    gemm_core(Xh, Wt, bias, z, r16, t16, nullptr, sm);
}

__global__ __launch_bounds__(256) void gemm_out(
    const _Float16* __restrict__ A, const _Float16* __restrict__ Wt,
    const float* __restrict__ bias, float* __restrict__ out)
{
    __shared__ char sm[49152];
    gemm_core(A, Wt, bias, 3, nullptr, nullptr, out, sm);
}

// ---------------------------------------------------------------------------
// converts
// ---------------------------------------------------------------------------
__global__ __launch_bounds__(256) void conv_x_kernel(
    const float* __restrict__ x, _Float16* __restrict__ xh)
{
    const int i = blockIdx.x * 256 + threadIdx.x;
    float4 v = ((const float4*)x)[i];
    h4_t hv;
    hv[0] = (_Float16)v.x; hv[1] = (_Float16)v.y;
    hv[2] = (_Float16)v.z; hv[3] = (_Float16)v.w;
    ((h4_t*)xh)[i] = hv;
}

__global__ __launch_bounds__(256) void conv_wt4(
    const float* __restrict__ Wq, const float* __restrict__ Wk,
    const float* __restrict__ Wv, const float* __restrict__ Wo,
    _Float16* __restrict__ WtQKV, _Float16* __restrict__ WtO)
{
    __shared__ float t[32][33];
    const int z = blockIdx.z;
    const float* W = (z == 0) ? Wq : (z == 1) ? Wk : (z == 2) ? Wv : Wo;
    _Float16* Wt = (z < 3) ? WtQKV + (size_t)z * DM * HD_ : WtO;
    const int bx = blockIdx.x * 32, by = blockIdx.y * 32;
    const int tx = threadIdx.x, ty = threadIdx.y;
#pragma unroll
    for (int i = 0; i < 4; ++i)
        t[ty + 8 * i][tx] = W[(size_t)(by + ty + 8 * i) * HD_ + bx + tx];
    __syncthreads();
#pragma unroll
    for (int i = 0; i < 4; ++i)
        Wt[(size_t)(bx + ty + 8 * i) * DM + by + tx] = (_Float16)t[tx][ty + 8 * i];
}

// ---------------------------------------------------------------------------
// chunk_sums: states^T[d][i] (f16, transposed) + z row via ones-row MFMA trick
// ---------------------------------------------------------------------------
__global__ __launch_bounds__(256) void chunk_sums(
    const _Float16* __restrict__ KT, const _Float16* __restrict__ VT,
    _Float16* __restrict__ states)
{
    __shared__ char sm[26880];
    _Float16* cwh = (_Float16*)(sm);        // 64 f16
    _Float16* swh = (_Float16*)(sm + 128);
    #define CS_KC 256
    #define CS_KS 8448
    #define CS_VT 16640   // 66 rows + overrun pad inside sm

    const int c = blockIdx.x, bh = blockIdx.y;
    const int tid = threadIdx.x, lane = tid & 63, w = tid >> 6;

    if (tid < 64) {
        float s_, c_;
        sincosf(ANG_STEP * (float)(c * 64 + tid), &s_, &c_);
        cwh[tid] = (_Float16)c_; swh[tid] = (_Float16)s_;
    }
    __syncthreads();

    const size_t ktb = (size_t)(bh * 64) * TSEQ + c * 64;
#pragma unroll
    for (int rnd = 0; rnd < 2; ++rnd) {
        int lin = rnd * 256 + tid;
        int r = lin >> 3, u = lin & 7;
        h8_t kv = *(const h8_t*)(KT + ktb + (size_t)r * TSEQ + u * 8);
        h8_t c8 = *(const h8_t*)&cwh[u * 8];
        h8_t s8 = *(const h8_t*)&swh[u * 8];
        int sb = (r * 128 + u * 16) ^ ((r & 7) << 4);
        *(h8_t*)(sm + CS_KC + sb) = kv * c8;
        *(h8_t*)(sm + CS_KS + sb) = kv * s8;
    }
    const _Float16* vtb = VT + (size_t)(bh * 64) * TSEQ + c * 64;
#pragma unroll
    for (int rnd = 0; rnd < 2; ++rnd) {
        int lin = rnd * 256 + tid;
        int r = lin >> 3, u = lin & 7;
        gload16(vtb + (size_t)r * TSEQ + (u ^ (r & 7)) * 8,
                sm + CS_VT + (rnd * 256 + w * 64) * 16);
    }
    if (tid < 8) {
        h8_t one;
#pragma unroll
        for (int e = 0; e < 8; ++e) one[e] = (_Float16)1.0f;
        *(h8_t*)(sm + CS_VT + 64 * 128 + tid * 16) = one;
    }
    __syncthreads();

    const int fr = lane & 15, rm = (lane >> 4) * 4;
    _Float16* stc = states + (size_t)(bh * NCH + c) * SSTR;

    for (int half = 0; half < 2; ++half) {
        const int ko = half ? CS_KS : CS_KC;
        f32x4 acc[4][5];
#pragma unroll
        for (int i = 0; i < 4; ++i)
#pragma unroll
            for (int j = 0; j < 5; ++j) acc[i][j] = (f32x4){0.f, 0.f, 0.f, 0.f};
#pragma unroll
        for (int ks = 0; ks < 2; ++ks) {
            const int fko = ks * 64 + (lane >> 4) * 16;
            h8_t af[4], bf[5];
#pragma unroll
            for (int i = 0; i < 4; ++i) {
                int row = i * 16 + fr;
                af[i] = *(const h8_t*)(sm + ko + ((row * 128 + fko) ^ ((row & 7) << 4)));
            }
#pragma unroll
            for (int j = 0; j < 5; ++j) {
                int row = j * 16 + fr;
                bf[j] = *(const h8_t*)(sm + CS_VT + ((row * 128 + fko) ^ ((row & 7) << 4)));
            }
#pragma unroll
            for (int i = 0; i < 4; ++i)
#pragma unroll
                for (int j = 0; j < 5; ++j)
                    acc[i][j] = __builtin_amdgcn_mfma_f32_16x16x32_f16(af[i], bf[j], acc[i][j], 0, 0, 0);
        }
        _Float16* dst = stc + half * SHALF;
#pragma unroll
        for (int j = 0; j < 5; ++j) {
            int n = j * 16 + fr;
#pragma unroll
            for (int i = 0; i < 4; ++i) {
                h4_t pk;
#pragma unroll
                for (int r = 0; r < 4; ++r) pk[r] = (_Float16)acc[i][j][r];
                if (n <= 64) *(h4_t*)(dst + (size_t)n * 64 + i * 16 + rm) = pk;
            }
        }
    }
}

// ---------------------------------------------------------------------------
// exclusive prefix over chunks, f16 state, fp32 running sums. grid (5,32)
// ---------------------------------------------------------------------------
__global__ __launch_bounds__(256) void scan_kernel(_Float16* __restrict__ states)
{
    const int e8 = blockIdx.x * 256 + threadIdx.x;
    if (e8 >= SSTR / 8) return;
    _Float16* p = states + (size_t)blockIdx.y * (NCH * (size_t)SSTR) + (size_t)e8 * 8;
    float run[8];
#pragma unroll
    for (int e = 0; e < 8; ++e) run[e] = 0.f;
    for (int c = 0; c < NCH; ++c) {
        h8_t v = *(const h8_t*)(p + (size_t)c * SSTR);
        h8_t ov;
#pragma unroll
        for (int e = 0; e < 8; ++e) {
            ov[e] = (_Float16)run[e];
            run[e] += (float)v[e];
        }
        *(h8_t*)(p + (size_t)c * SSTR) = ov;
    }
}

// ---------------------------------------------------------------------------
// MFMA attention: QK^T -> mask/scale -> (A.V + Qc.Sc + Qs.Ss) with den column
// output flushed via LDS (dead AT_K region) as coalesced h8 stores.
// ---------------------------------------------------------------------------
__global__ __launch_bounds__(256) void attn_mfma(
    const _Float16* __restrict__ Qh, const _Float16* __restrict__ Kh,
    const _Float16* __restrict__ VT, const _Float16* __restrict__ states,
    _Float16* __restrict__ atth)
{
    __shared__ char sm[53248];
    float* cwf = (float*)(sm);
    float* swf = (float*)(sm + 256);
    _Float16* cwh = (_Float16*)(sm + 512);
    _Float16* swh = (_Float16*)(sm + 640);
    #define AT_Q 768
    #define AT_K 8960
    #define AT_A 17152
    #define AT_V 25344
    #define AT_C 33792
    #define AT_S 43008

    const int c = blockIdx.x, bh = blockIdx.y;
    const int b = bh >> 4, h = bh & 15;
    const int tid = threadIdx.x, lane = tid & 63, w = tid >> 6;
    const int tok0 = b * TSEQ + c * 64;

    if (tid < 64) {
        float s_, c_;
        sincosf(ANG_STEP * (float)(c * 64 + tid), &s_, &c_);
        cwf[tid] = c_; swf[tid] = s_;
        cwh[tid] = (_Float16)c_; swh[tid] = (_Float16)s_;
    }

    const _Float16* stb = states + (size_t)(bh * NCH + c) * SSTR;
#pragma unroll
    for (int rnd = 0; rnd < 2; ++rnd) {
        int lin = rnd * 256 + tid;
        int r = lin >> 3, u = lin & 7;
        int su = (u ^ (r & 7)) * 8;
        char* lb = sm + (rnd * 256 + w * 64) * 16;
        gload16(Qh + (size_t)(tok0 + r) * HD_ + h * 64 + su, lb + AT_Q);
        gload16(Kh + (size_t)(tok0 + r) * HD_ + h * 64 + su, lb + AT_K);
        gload16(VT + (size_t)(bh * 64 + r) * TSEQ + c * 64 + su, lb + AT_V);
    }
#pragma unroll
    for (int rnd = 0; rnd < 3; ++rnd) {
        if (rnd < 2 || tid < 64) {
            int lin = rnd * 256 + tid;
            int r = lin >> 3, u = lin & 7;
            int su = (u ^ (r & 7)) * 8;
            char* lb = sm + (rnd * 256 + w * 64) * 16;
            gload16(stb + (size_t)r * 64 + su, lb + AT_C);
            gload16(stb + SHALF + (size_t)r * 64 + su, lb + AT_S);
        }
    }
    if (tid < 8) {
        h8_t one;
#pragma unroll
        for (int e = 0; e < 8; ++e) one[e] = (_Float16)1.0f;
        *(h8_t*)(sm + AT_V + 64 * 128 + tid * 16) = one;
    }
    __syncthreads();

    const int fr = lane & 15;
    // ---- QK^T: D[s][tt] = K.Q^T
    f32x4 dt[4][4];
#pragma unroll
    for (int i = 0; i < 4; ++i)
#pragma unroll
        for (int j = 0; j < 4; ++j) dt[i][j] = (f32x4){0.f, 0.f, 0.f, 0.f};
#pragma unroll
    for (int ks = 0; ks < 2; ++ks) {
        const int fko = ks * 64 + (lane >> 4) * 16;
        h8_t ak[4], bq[4];
#pragma unroll
        for (int i = 0; i < 4; ++i) {
            int row = i * 16 + fr;
            int sb = (row * 128 + fko) ^ ((row & 7) << 4);
            ak[i] = *(const h8_t*)(sm + AT_K + sb);
            bq[i] = *(const h8_t*)(sm + AT_Q + sb);
        }
#pragma unroll
        for (int i = 0; i < 4; ++i)
#pragma unroll
            for (int j = 0; j < 4; ++j)
                dt[i][j] = __builtin_amdgcn_mfma_f32_16x16x32_f16(ak[i], bq[j], dt[i][j], 0, 0, 0);
    }
    // ---- mask + cos-reweight, write A[tt][s] f16 (swizzled)
    {
        const int sr0 = (lane >> 4) * 4;
#pragma unroll
        for (int j = 0; j < 4; ++j) {
            const int tt = j * 16 + fr;
            const float cwt = cwf[tt], swt = swf[tt];
#pragma unroll
            for (int i = 0; i < 4; ++i) {
                const int s0 = i * 16 + sr0;
                h4_t pk;
#pragma unroll
                for (int r = 0; r < 4; ++r) {
                    int s = s0 + r;
                    float f = cwt * cwf[s] + swt * swf[s];
                    float a = (s <= tt) ? dt[i][j][r] * f : 0.f;
                    pk[r] = (_Float16)a;
                }
                int sb = (tt * 128 + s0 * 2) ^ ((tt & 7) << 4);
                *(h4_t*)(sm + AT_A + sb) = pk;
            }
        }
    }
    __syncthreads();

    // ---- O = A.V + Qc.ScT^T + Qs.SsT^T ; col 64 = den (intra + inter)
    f32x4 o[4][5];
#pragma unroll
    for (int i = 0; i < 4; ++i)
#pragma unroll
        for (int j = 0; j < 5; ++j) o[i][j] = (f32x4){0.f, 0.f, 0.f, 0.f};
#pragma unroll
    for (int ks = 0; ks < 2; ++ks) {
        const int fko = ks * 64 + (lane >> 4) * 16;
        h8_t aa[4], aqc[4], aqs[4];
#pragma unroll
        for (int i = 0; i < 4; ++i) {
            int row = i * 16 + fr;
            int sb = (row * 128 + fko) ^ ((row & 7) << 4);
            aa[i] = *(const h8_t*)(sm + AT_A + sb);
            h8_t q8 = *(const h8_t*)(sm + AT_Q + sb);
            aqc[i] = q8 * cwh[row];
            aqs[i] = q8 * swh[row];
        }
#pragma unroll
        for (int j = 0; j < 5; ++j) {
            int row = j * 16 + fr;
            int sb = (row * 128 + fko) ^ ((row & 7) << 4);
            h8_t bv = *(const h8_t*)(sm + AT_V + sb);
            h8_t bc = *(const h8_t*)(sm + AT_C + sb);
            h8_t bs = *(const h8_t*)(sm + AT_S + sb);
#pragma unroll
            for (int i = 0; i < 4; ++i) {
                o[i][j] = __builtin_amdgcn_mfma_f32_16x16x32_f16(aa[i],  bv, o[i][j], 0, 0, 0);
                o[i][j] = __builtin_amdgcn_mfma_f32_16x16x32_f16(aqc[i], bc, o[i][j], 0, 0, 0);
                o[i][j] = __builtin_amdgcn_mfma_f32_16x16x32_f16(aqs[i], bs, o[i][j], 0, 0, 0);
            }
        }
    }
    // ---- den broadcast + LDS-staged coalesced output (reuse dead AT_K, 8KB)
    char* Ce = sm + AT_K;   // 64 t-rows x 64 d cols f16, 128B rows, swizzled
    const int rm = (lane >> 4) * 4;
#pragma unroll
    for (int i = 0; i < 4; ++i) {
        float rden[4];
#pragma unroll
        for (int r = 0; r < 4; ++r)
            rden[r] = 1.0f / fmaxf(__shfl(o[i][4][r], lane & 48), 1e-6f);
#pragma unroll
        for (int j = 0; j < 4; ++j) {
            const int col = j * 16 + fr;
#pragma unroll
            for (int r = 0; r < 4; ++r) {
                const int t = i * 16 + rm + r;
                const int byte = ((t << 7) + (col << 1)) ^ ((t & 7) << 4);
                *(_Float16*)(Ce + byte) = (_Float16)(o[i][j][r] * rden[r]);
            }
        }
    }
    __syncthreads();
#pragma unroll
    for (int p = 0; p < 2; ++p) {
        const int lin = p * 256 + tid;
        const int t = lin >> 3, d8 = lin & 7;
        h8_t v = *(const h8_t*)(Ce + (t << 7) + ((d8 ^ (t & 7)) << 4));
        *(h8_t*)(atth + (size_t)(tok0 + t) * HD_ + h * 64 + d8 * 8) = v;
    }
}

// ---------------------------------------------------------------------------
extern "C" void kernel_launch(void* const* d_in, const int* in_sizes, int n_in,
                              void* d_out, int out_size, void* d_ws, size_t ws_size,
                              hipStream_t stream)
{
    const float* x  = (const float*)d_in[0];
    const float* Wq = (const float*)d_in[1];
    const float* bq = (const float*)d_in[2];
    const float* Wk = (const float*)d_in[3];
    const float* bk = (const float*)d_in[4];
    const float* Wv = (const float*)d_in[5];
    const float* bv = (const float*)d_in[6];
    const float* Wo = (const float*)d_in[7];
    const float* bo = (const float*)d_in[8];
    float* out = (float*)d_out;

    _Float16* ws = (_Float16*)d_ws;
    _Float16* Xh     = ws;                                  // NTOK*DM
    _Float16* WtQKV  = Xh + (size_t)NTOK * DM;              // 3*DM*HD_
    _Float16* WtO    = WtQKV + 3 * (size_t)DM * HD_;        // DM*HD_
    _Float16* Qh     = WtO + (size_t)DM * HD_;              // NTOK*HD_
    _Float16* Kh     = Qh + (size_t)NTOK * HD_;
    _Float16* KT     = Kh + (size_t)NTOK * HD_;             // [bh][64][4096]
    _Float16* VT     = KT + (size_t)NTOK * HD_;
    _Float16* atth   = VT + (size_t)NTOK * HD_;
    _Float16* states = atth + (size_t)NTOK * HD_;           // 32*64*SSTR

    dim3 tb(256);
    hipLaunchKernelGGL(conv_x_kernel, dim3(NTOK * DM / 1024), tb, 0, stream, x, Xh);
    hipLaunchKernelGGL(conv_wt4, dim3(32, 32, 4), dim3(32, 8), 0, stream,
                       Wq, Wk, Wv, Wo, WtQKV, WtO);
    hipLaunchKernelGGL(gemm_qkv, dim3(64, 8, 3), tb, 0, stream,
                       Xh, WtQKV, bq, bk, bv, Qh, Kh, KT, VT);
    hipLaunchKernelGGL(chunk_sums, dim3(NCH, 32), tb, 0, stream, KT, VT, states);
    hipLaunchKernelGGL(scan_kernel, dim3(5, 32), tb, 0, stream, states);
    hipLaunchKernelGGL(attn_mfma, dim3(NCH, 32), tb, 0, stream, Qh, Kh, VT, states, atth);
    hipLaunchKernelGGL(gemm_out, dim3(64, 8), tb, 0, stream, atth, WtO, bo, out);
}